// Round 19
// baseline (679.572 us; speedup 1.0000x reference)
//
#include <hip/hip_runtime.h>
#include <math.h>

// Problem constants
#define B_    512
#define T_    256
#define DIN   64
#define DS    64
#define KK    128   // DIN + DS
#define NN    2048
#define DOUT  10

// Tiling: 128 WGs = NTILES(4) x BTILES(32), 512 thr (8 waves), BT=16.
// Full M=16 MFMA rows (no zero padding); 32 independent 4-WG chains.
#define NT      512
#define BT      16
#define NTILES  (NN / NT)      // 4
#define BTILES  (B_ / BT)      // 32
#define THREADS 512
#define NWG     (NTILES * BTILES)   // 128

// Workspace: psq (u64 tagged partials, double-buffered) | EtSw | SdSw
#define PSQ_ELEMS  ((size_t)BTILES * NTILES * BT * DS)  // 131072 u64 per buffer
#define PS_FLOATS  (4 * PSQ_ELEMS)                      // 2 buffers as float count
#define ETSW_OFF   PS_FLOATS
#define ETSW_F16   ((size_t)KK * NN)                    // 262144 f16 = 512 KB
#define SDSW_OFF   (ETSW_OFF + ETSW_F16 / 2)
#define SDSW_F16   ((size_t)NN * DS)                    // 131072 f16 = 256 KB

typedef _Float16 half8 __attribute__((ext_vector_type(8)));
typedef float    f32x4 __attribute__((ext_vector_type(4)));

__global__ __launch_bounds__(256) void pre_kernel(const float* __restrict__ enc,
                                                  const float* __restrict__ sd,
                                                  float* __restrict__ ws,
                                                  float* __restrict__ out) {
    size_t i = (size_t)blockIdx.x * blockDim.x + threadIdx.x;
    size_t stride = (size_t)gridDim.x * blockDim.x;
    // zero tagged-partial buffers (tag 0 never matches: consumer tags >= 1)
    unsigned long long* psq = (unsigned long long*)ws;
    for (size_t x = i; x < 2 * PSQ_ELEMS; x += stride) psq[x] = 0ull;
    // EtSw: B-fragments, 8-wave ownership (R13-verified, unchanged).
    _Float16* EtSw = (_Float16*)(ws + ETSW_OFF);
    for (size_t x = i; x < (size_t)KK * NN; x += stride) {
        const int j     = (int)(x & 7);
        const int lane  = (int)((x >> 3) & 63);
        const int ktile = (int)((x >> 9) & 3);
        const int ntile = (int)((x >> 11) & 3);
        const int w     = (int)((x >> 13) & 7);
        const int nt    = (int)(x >> 16);
        const int n = nt * 512 + w * 64 + ntile * 16 + (lane & 15);
        const int k = ktile * 32 + ((lane >> 4) << 3) + j;
        EtSw[x] = (_Float16)enc[(size_t)n * KK + k];
    }
    // SdSw: decode B-fragments, full-K ownership (R18-verified, unchanged).
    _Float16* SdSw = (_Float16*)(ws + SDSW_OFF);
    for (size_t x = i; x < (size_t)NN * DS; x += stride) {
        const int j     = (int)(x & 7);
        const int lane  = (int)((x >> 3) & 63);
        const int ktile = (int)((x >> 9) & 15);
        const int cg    = (int)((x >> 13) & 3);
        const int nt    = (int)(x >> 15);
        const int n = nt * 512 + ktile * 32 + ((lane >> 4) << 3) + j;
        const int c = cg * 16 + (lane & 15);
        SdSw[x] = (_Float16)sd[(size_t)n * DS + c];
    }
    for (size_t x = i; x < (size_t)B_ * DOUT; x += stride) out[x] = 0.0f;
}

// R18 core (tagged-payload exchange, spec-poll, 3 barriers, register-resident
// weights; 557 us steady) retiled to BT=16: every MFMA M-row is real (the 8
// zero-pad rows deleted), chains drop 64 -> 32, total MALL traffic halves.
// Per-thread fan-in: 2 state elements x 4 partials = 8 tagged loads, one RTT.
// Protocol induction unchanged: B1 orders all fan-in reads before any store;
// producer writes psq[t&1] only after observing tags t in psq[(t-1)&1].
__global__ __launch_bounds__(THREADS, 1) void persist_kernel(
    const float* __restrict__ seq,          // [B][T][DIN]
    const _Float16* __restrict__ EtSw,      // encoder B-fragments
    const _Float16* __restrict__ SdSw,      // state-decoder B-fragments
    const float* __restrict__ bias,
    const float* __restrict__ gain,
    const float* __restrict__ dec,          // [NN][DOUT]
    unsigned long long* __restrict__ psq,   // [2][BTILES][NTILES][BT][DS] tagged
    float* __restrict__ out)
{
    __shared__ _Float16 xh[16][136];  // x_aug f16 (A-operand), all 16 rows real
    __shared__ _Float16 Ash[16][520]; // activations f16 (A-operand for decode)

    const int tid = threadIdx.x;
    const int nt = blockIdx.x & (NTILES - 1);
    const int bt = blockIdx.x >> 2;
    const int n0 = nt * NT;
    const int b0 = bt * BT;

    const int w = tid >> 6;            // wave 0..7
    const int l = tid & 63;
    const int m16 = l & 15;            // fragment row/col index
    const int q8  = (l >> 4) << 3;     // fragment k sub-offset

    const _Float16* EtW = EtSw + ((size_t)(nt * 8 + w) << 13);
    const _Float16* SdW = SdSw + ((size_t)(nt * 4 + (w & 3)) << 13);

    // ---- register-resident weight fragments (loaded once) ----
    half8 etf[4][4];   // [ntile][ktile]
    #pragma unroll
    for (int n4 = 0; n4 < 4; ++n4)
        #pragma unroll
        for (int kt = 0; kt < 4; ++kt)
            etf[n4][kt] = *(const half8*)&EtW[(n4 << 11) + (kt << 9) + (size_t)l * 8];
    half8 sdf[16];     // full-K decode fragments (used by waves 0..3)
    #pragma unroll
    for (int kt = 0; kt < 16; ++kt)
        sdf[kt] = *(const half8*)&SdW[(kt << 9) + (size_t)l * 8];

    // epilogue params
    float gv[4], bv[4];
    #pragma unroll
    for (int n4 = 0; n4 < 4; ++n4) {
        gv[n4] = gain[n0 + w * 64 + n4 * 16 + m16];
        bv[n4] = bias[n0 + w * 64 + n4 * 16 + m16];
    }

    // fan-in: thread handles state elements (row=w, col=l) and (row=w+8, col=l)
    // psq addr(p,row,col) = colbase + p*(BT*DS) + row*DS + col
    const size_t colbase = (size_t)bt * NTILES * BT * DS;
    const size_t fb0 = colbase + (size_t)w * DS + l;
    const size_t fb1 = colbase + (size_t)(w + 8) * DS + l;

    // preamble: stage u_0 (16 rows x 64 cols)
    if (tid < 256) {
        const int r = tid >> 4, c = (tid & 15) << 2;
        const float4 uv = *(const float4*)&seq[((size_t)(b0 + r) * T_ + 0) * DIN + c];
        _Float16* p = &xh[r][c];
        p[0] = (_Float16)uv.x; p[1] = (_Float16)uv.y;
        p[2] = (_Float16)uv.z; p[3] = (_Float16)uv.w;
    }
    __syncthreads();

    for (int t = 0; t < T_; ++t) {
        // ---- speculative poll issue: 8 loads in flight during encode-A ----
        const unsigned long long* pb = psq + (size_t)((t - 1) & 1) * PSQ_ELEMS;
        unsigned long long a0 = 0, a1 = 0, a2 = 0, a3 = 0;
        unsigned long long b0v = 0, b1v = 0, b2v = 0, b3v = 0;
        if (t > 0) {
            a0 = __hip_atomic_load(pb + fb0 + 0 * (BT * DS), __ATOMIC_RELAXED, __HIP_MEMORY_SCOPE_AGENT);
            a1 = __hip_atomic_load(pb + fb0 + 1 * (BT * DS), __ATOMIC_RELAXED, __HIP_MEMORY_SCOPE_AGENT);
            a2 = __hip_atomic_load(pb + fb0 + 2 * (BT * DS), __ATOMIC_RELAXED, __HIP_MEMORY_SCOPE_AGENT);
            a3 = __hip_atomic_load(pb + fb0 + 3 * (BT * DS), __ATOMIC_RELAXED, __HIP_MEMORY_SCOPE_AGENT);
            b0v = __hip_atomic_load(pb + fb1 + 0 * (BT * DS), __ATOMIC_RELAXED, __HIP_MEMORY_SCOPE_AGENT);
            b1v = __hip_atomic_load(pb + fb1 + 1 * (BT * DS), __ATOMIC_RELAXED, __HIP_MEMORY_SCOPE_AGENT);
            b2v = __hip_atomic_load(pb + fb1 + 2 * (BT * DS), __ATOMIC_RELAXED, __HIP_MEMORY_SCOPE_AGENT);
            b3v = __hip_atomic_load(pb + fb1 + 3 * (BT * DS), __ATOMIC_RELAXED, __HIP_MEMORY_SCOPE_AGENT);
        }

        // ---- encode phase A: k-tiles 0,1 (u_t staged last step) ----
        f32x4 acc[4];
        #pragma unroll
        for (int n4 = 0; n4 < 4; ++n4) acc[n4] = (f32x4){0.f, 0.f, 0.f, 0.f};
        {
            const half8 af0 = *(const half8*)&xh[m16][q8];
            const half8 af1 = *(const half8*)&xh[m16][32 + q8];
            #pragma unroll
            for (int n4 = 0; n4 < 4; ++n4) {
                acc[n4] = __builtin_amdgcn_mfma_f32_16x16x32_f16(af0, etf[n4][0], acc[n4], 0, 0, 0);
                acc[n4] = __builtin_amdgcn_mfma_f32_16x16x32_f16(af1, etf[n4][1], acc[n4], 0, 0, 0);
            }
        }

        // ---- acquire s(t-1): check speculative values, retry on stale tags ----
        if (t > 0) {
            const unsigned utag = (unsigned)t;
            for (;;) {
                if ((unsigned)(a0 >> 32) == utag && (unsigned)(a1 >> 32) == utag &&
                    (unsigned)(a2 >> 32) == utag && (unsigned)(a3 >> 32) == utag &&
                    (unsigned)(b0v >> 32) == utag && (unsigned)(b1v >> 32) == utag &&
                    (unsigned)(b2v >> 32) == utag && (unsigned)(b3v >> 32) == utag)
                    break;
                a0 = __hip_atomic_load(pb + fb0 + 0 * (BT * DS), __ATOMIC_RELAXED, __HIP_MEMORY_SCOPE_AGENT);
                a1 = __hip_atomic_load(pb + fb0 + 1 * (BT * DS), __ATOMIC_RELAXED, __HIP_MEMORY_SCOPE_AGENT);
                a2 = __hip_atomic_load(pb + fb0 + 2 * (BT * DS), __ATOMIC_RELAXED, __HIP_MEMORY_SCOPE_AGENT);
                a3 = __hip_atomic_load(pb + fb0 + 3 * (BT * DS), __ATOMIC_RELAXED, __HIP_MEMORY_SCOPE_AGENT);
                b0v = __hip_atomic_load(pb + fb1 + 0 * (BT * DS), __ATOMIC_RELAXED, __HIP_MEMORY_SCOPE_AGENT);
                b1v = __hip_atomic_load(pb + fb1 + 1 * (BT * DS), __ATOMIC_RELAXED, __HIP_MEMORY_SCOPE_AGENT);
                b2v = __hip_atomic_load(pb + fb1 + 2 * (BT * DS), __ATOMIC_RELAXED, __HIP_MEMORY_SCOPE_AGENT);
                b3v = __hip_atomic_load(pb + fb1 + 3 * (BT * DS), __ATOMIC_RELAXED, __HIP_MEMORY_SCOPE_AGENT);
            }
            const float s0 = __uint_as_float((unsigned)a0) + __uint_as_float((unsigned)a1)
                           + __uint_as_float((unsigned)a2) + __uint_as_float((unsigned)a3);
            const float s1 = __uint_as_float((unsigned)b0v) + __uint_as_float((unsigned)b1v)
                           + __uint_as_float((unsigned)b2v) + __uint_as_float((unsigned)b3v);
            xh[w][DIN + l]     = (_Float16)s0;
            xh[w + 8][DIN + l] = (_Float16)s1;
        } else {
            xh[w][DIN + l]     = (_Float16)0.f;
            xh[w + 8][DIN + l] = (_Float16)0.f;
        }
        __syncthreads();   // B1: state half ready

        // ---- encode phase B: k-tiles 2,3 ----
        {
            const half8 af2 = *(const half8*)&xh[m16][64 + q8];
            const half8 af3 = *(const half8*)&xh[m16][96 + q8];
            #pragma unroll
            for (int n4 = 0; n4 < 4; ++n4) {
                acc[n4] = __builtin_amdgcn_mfma_f32_16x16x32_f16(af2, etf[n4][2], acc[n4], 0, 0, 0);
                acc[n4] = __builtin_amdgcn_mfma_f32_16x16x32_f16(af3, etf[n4][3], acc[n4], 0, 0, 0);
            }
        }

        // ---- epilogue: all 16 rows real; every lane writes 4 rows x 4 ntiles ----
        {
            const int rq = (l >> 4) << 2;
            #pragma unroll
            for (int n4 = 0; n4 < 4; ++n4) {
                const int n = w * 64 + n4 * 16 + m16;
                Ash[rq + 0][n] = (_Float16)fabsf(gv[n4] * acc[n4][0] + bv[n4]);
                Ash[rq + 1][n] = (_Float16)fabsf(gv[n4] * acc[n4][1] + bv[n4]);
                Ash[rq + 2][n] = (_Float16)fabsf(gv[n4] * acc[n4][2] + bv[n4]);
                Ash[rq + 3][n] = (_Float16)fabsf(gv[n4] * acc[n4][3] + bv[n4]);
            }
        }
        __syncthreads();   // B2: activations ready

        if (t == T_ - 1) {
            // ---- final projection: out += A_tile @ dec_tile ----
            for (int idx = tid; idx < BT * DOUT; idx += THREADS) {
                const int r = idx / DOUT;
                const int d = idx % DOUT;
                float o = 0.f;
                #pragma unroll 8
                for (int n = 0; n < NT; ++n)
                    o += (float)Ash[r][n] * dec[(size_t)(n0 + n) * DOUT + d];
                atomicAdd(&out[(size_t)(b0 + r) * DOUT + d], o);
            }
            return;
        }

        // ---- decode (waves 0-3, full K=512) + u_{t+1} staging (waves 4-7) ----
        if (w < 4) {
            f32x4 d0 = (f32x4){0.f, 0.f, 0.f, 0.f};
            f32x4 d1 = (f32x4){0.f, 0.f, 0.f, 0.f};
            #pragma unroll
            for (int kt = 0; kt < 16; kt += 2) {
                const half8 ax0 = *(const half8*)&Ash[m16][kt * 32 + q8];
                d0 = __builtin_amdgcn_mfma_f32_16x16x32_f16(ax0, sdf[kt], d0, 0, 0, 0);
                const half8 ax1 = *(const half8*)&Ash[m16][(kt + 1) * 32 + q8];
                d1 = __builtin_amdgcn_mfma_f32_16x16x32_f16(ax1, sdf[kt + 1], d1, 0, 0, 0);
            }
            d0[0] += d1[0]; d0[1] += d1[1]; d0[2] += d1[2]; d0[3] += d1[3];
            // C/D: col = 16w+m16; rows rq..rq+3 (all real) across 64 lanes
            {
                const int rq = (l >> 4) << 2;
                unsigned long long* pw = psq + (size_t)(t & 1) * PSQ_ELEMS
                    + colbase + (size_t)nt * (BT * DS) + 16 * w + m16;
                const unsigned long long tg = (unsigned long long)(unsigned)(t + 1) << 32;
                #pragma unroll
                for (int r = 0; r < 4; ++r) {
                    __hip_atomic_store(pw + (size_t)(rq + r) * DS,
                                       tg | (unsigned long long)__float_as_uint(d0[r]),
                                       __ATOMIC_RELAXED, __HIP_MEMORY_SCOPE_AGENT);
                }
            }
        } else {
            // stage u_{t+1}: 4 waves x 64 lanes = 256 float4 loads (16 rows)
            const int idx = ((w - 4) << 6) + l;     // 0..255
            const int r = idx >> 4, c = (idx & 15) << 2;
            const float4 uv =
                *(const float4*)&seq[((size_t)(b0 + r) * T_ + (t + 1)) * DIN + c];
            _Float16* p = &xh[r][c];
            p[0] = (_Float16)uv.x; p[1] = (_Float16)uv.y;
            p[2] = (_Float16)uv.z; p[3] = (_Float16)uv.w;
        }
        __syncthreads();   // B3: decode reads of Ash done + u_{t+1} staged
        // no drain, no counter — tag rides with the data
    }
}

extern "C" void kernel_launch(void* const* d_in, const int* in_sizes, int n_in,
                              void* d_out, int out_size, void* d_ws, size_t ws_size,
                              hipStream_t stream) {
    const float* seq  = (const float*)d_in[0];
    const float* enc  = (const float*)d_in[1];
    const float* bias = (const float*)d_in[2];
    const float* gain = (const float*)d_in[3];
    const float* sd   = (const float*)d_in[4];
    const float* dec  = (const float*)d_in[5];
    float* out = (float*)d_out;
    float* ws  = (float*)d_ws;   // psq[2] (2 MB) | EtSw | SdSw  (~2.8 MB)

    pre_kernel<<<dim3(1024), dim3(256), 0, stream>>>(enc, sd, ws, out);

    unsigned long long* psq = (unsigned long long*)ws;
    const _Float16* EtSw = (const _Float16*)(ws + ETSW_OFF);
    const _Float16* SdSw = (const _Float16*)(ws + SDSW_OFF);

    persist_kernel<<<dim3(NWG), dim3(THREADS), 0, stream>>>(
        seq, EtSw, SdSw, bias, gain, dec, psq, out);
}

// Round 20
// 610.237 us; speedup vs baseline: 1.1136x; 1.1136x over previous
//
#include <hip/hip_runtime.h>
#include <math.h>

// Problem constants
#define B_    512
#define T_    256
#define DIN   64
#define DS    64
#define KK    128   // DIN + DS
#define NN    2048
#define DOUT  10

// Tiling: 256 WGs = NTILES(4) x BTILES(64), 512 thr (8 waves), 1 WG/CU.
#define NT      512
#define BT      8
#define NTILES  (NN / NT)      // 4
#define BTILES  (B_ / BT)      // 64
#define THREADS 512
#define NWG     (NTILES * BTILES)   // 256

// Workspace: psq (u64 tagged partials, double-buffered) | EtSw | SdSw
#define PSQ_ELEMS  ((size_t)BTILES * NTILES * BT * DS)  // 131072 u64 per buffer
#define PS_FLOATS  (4 * PSQ_ELEMS)                      // 2 buffers as float count
#define ETSW_OFF   PS_FLOATS
#define ETSW_F16   ((size_t)KK * NN)                    // 262144 f16 = 512 KB
#define SDSW_OFF   (ETSW_OFF + ETSW_F16 / 2)
#define SDSW_F16   ((size_t)NN * DS)                    // 131072 f16 = 256 KB

typedef _Float16 half8 __attribute__((ext_vector_type(8)));
typedef float    f32x4 __attribute__((ext_vector_type(4)));

__global__ __launch_bounds__(256) void pre_kernel(const float* __restrict__ enc,
                                                  const float* __restrict__ sd,
                                                  float* __restrict__ ws,
                                                  float* __restrict__ out) {
    size_t i = (size_t)blockIdx.x * blockDim.x + threadIdx.x;
    size_t stride = (size_t)gridDim.x * blockDim.x;
    // zero tagged-partial buffers (tag 0 never matches: consumer tags >= 1)
    unsigned long long* psq = (unsigned long long*)ws;
    for (size_t x = i; x < 2 * PSQ_ELEMS; x += stride) psq[x] = 0ull;
    // EtSw: B-fragments, 8-wave ownership (R13-verified).
    _Float16* EtSw = (_Float16*)(ws + ETSW_OFF);
    for (size_t x = i; x < (size_t)KK * NN; x += stride) {
        const int j     = (int)(x & 7);
        const int lane  = (int)((x >> 3) & 63);
        const int ktile = (int)((x >> 9) & 3);
        const int ntile = (int)((x >> 11) & 3);
        const int w     = (int)((x >> 13) & 7);
        const int nt    = (int)(x >> 16);
        const int n = nt * 512 + w * 64 + ntile * 16 + (lane & 15);
        const int k = ktile * 32 + ((lane >> 4) << 3) + j;
        EtSw[x] = (_Float16)enc[(size_t)n * KK + k];
    }
    // SdSw: decode B-fragments, full-K ownership (R18-verified).
    _Float16* SdSw = (_Float16*)(ws + SDSW_OFF);
    for (size_t x = i; x < (size_t)NN * DS; x += stride) {
        const int j     = (int)(x & 7);
        const int lane  = (int)((x >> 3) & 63);
        const int ktile = (int)((x >> 9) & 15);
        const int cg    = (int)((x >> 13) & 3);
        const int nt    = (int)(x >> 15);
        const int n = nt * 512 + ktile * 32 + ((lane >> 4) << 3) + j;
        const int c = cg * 16 + (lane & 15);
        SdSw[x] = (_Float16)sd[(size_t)n * DS + c];
    }
    for (size_t x = i; x < (size_t)B_ * DOUT; x += stride) out[x] = 0.0f;
}

// R18 exact revert (best measured: 557 us steady / 609 mean). Tagged-payload
// exchange: each partial is an 8B packed (tag<<32 | f32) relaxed-agent store;
// consumers spec-issue their 4 tagged loads before encode-A and tag-check
// after (one RTT hidden), retry only on stale tags. Full-K decode on waves
// 0-3 (no cross-wave reduce); waves 4-7 stage u_{t+1} during the decode
// window. 3 barriers/step. R19's BT=16 retile regressed (+10%): fan-in width
// per thread doubled 4->8 tags and max-of-8 producer skew dominates in this
// latency-bound regime — fan-in width is the knob, keep it at 4.
// launch_bounds(512,1): sdf[16] needs headroom; (512,2)'s 128-VGPR cap would
// spill (R9 lesson). Grid = 256 = CU count -> 1 WG/CU.
__global__ __launch_bounds__(THREADS, 1) void persist_kernel(
    const float* __restrict__ seq,          // [B][T][DIN]
    const _Float16* __restrict__ EtSw,      // encoder B-fragments
    const _Float16* __restrict__ SdSw,      // state-decoder B-fragments
    const float* __restrict__ bias,
    const float* __restrict__ gain,
    const float* __restrict__ dec,          // [NN][DOUT]
    unsigned long long* __restrict__ psq,   // [2][BTILES][NTILES][BT][DS] tagged
    float* __restrict__ out)
{
    __shared__ _Float16 xh[16][136];  // x_aug f16 (A-operand), rows 8..15 zero
    __shared__ _Float16 Ash[16][520]; // activations f16 (A-operand for decode)

    const int tid = threadIdx.x;
    const int nt = blockIdx.x & (NTILES - 1);
    const int bt = blockIdx.x >> 2;
    const int n0 = nt * NT;
    const int b0 = bt * BT;

    const int w = tid >> 6;            // wave 0..7
    const int l = tid & 63;
    const int rs = tid >> 6;           // fan-in row 0..7
    const int cs = tid & 63;           // fan-in col
    const int m16 = l & 15;            // fragment row/col index
    const int q8  = (l >> 4) << 3;     // fragment k sub-offset

    const _Float16* EtW = EtSw + ((size_t)(nt * 8 + w) << 13);
    const _Float16* SdW = SdSw + ((size_t)(nt * 4 + (w & 3)) << 13);

    // ---- register-resident weight fragments (loaded once) ----
    half8 etf[4][4];   // [ntile][ktile]
    #pragma unroll
    for (int n4 = 0; n4 < 4; ++n4)
        #pragma unroll
        for (int kt = 0; kt < 4; ++kt)
            etf[n4][kt] = *(const half8*)&EtW[(n4 << 11) + (kt << 9) + (size_t)l * 8];
    half8 sdf[16];     // full-K decode fragments (used by waves 0..3)
    #pragma unroll
    for (int kt = 0; kt < 16; ++kt)
        sdf[kt] = *(const half8*)&SdW[(kt << 9) + (size_t)l * 8];

    // epilogue params
    float gv[4], bv[4];
    #pragma unroll
    for (int n4 = 0; n4 < 4; ++n4) {
        gv[n4] = gain[n0 + w * 64 + n4 * 16 + m16];
        bv[n4] = bias[n0 + w * 64 + n4 * 16 + m16];
    }

    // fan-in base: this thread's 4 partials (p = 0..3), stride BT*DS u64s
    const size_t fan_base = ((size_t)bt * NTILES) * BT * DS + (size_t)rs * DS + cs;

    // preamble: zero xh (rows 8..15 stay zero), stage u_0
    {
        unsigned int* xz = (unsigned int*)&xh[0][0];
        for (int i2 = tid; i2 < 16 * 136 / 2; i2 += THREADS) xz[i2] = 0u;
    }
    __syncthreads();
    if (tid < 128) {
        const int r = tid >> 4, c = (tid & 15) << 2;
        const float4 uv = *(const float4*)&seq[((size_t)(b0 + r) * T_ + 0) * DIN + c];
        _Float16* p = &xh[r][c];
        p[0] = (_Float16)uv.x; p[1] = (_Float16)uv.y;
        p[2] = (_Float16)uv.z; p[3] = (_Float16)uv.w;
    }
    __syncthreads();

    for (int t = 0; t < T_; ++t) {
        // ---- speculative poll issue: loads in flight during encode-A ----
        const unsigned long long* pb =
            psq + (size_t)((t - 1) & 1) * PSQ_ELEMS + fan_base;
        unsigned long long v0 = 0, v1 = 0, v2 = 0, v3 = 0;
        if (t > 0) {
            v0 = __hip_atomic_load(pb + 0 * (BT * DS), __ATOMIC_RELAXED, __HIP_MEMORY_SCOPE_AGENT);
            v1 = __hip_atomic_load(pb + 1 * (BT * DS), __ATOMIC_RELAXED, __HIP_MEMORY_SCOPE_AGENT);
            v2 = __hip_atomic_load(pb + 2 * (BT * DS), __ATOMIC_RELAXED, __HIP_MEMORY_SCOPE_AGENT);
            v3 = __hip_atomic_load(pb + 3 * (BT * DS), __ATOMIC_RELAXED, __HIP_MEMORY_SCOPE_AGENT);
        }

        // ---- encode phase A: k-tiles 0,1 (u_t staged last step; no barrier) ----
        f32x4 acc[4];
        #pragma unroll
        for (int n4 = 0; n4 < 4; ++n4) acc[n4] = (f32x4){0.f, 0.f, 0.f, 0.f};
        {
            const half8 af0 = *(const half8*)&xh[m16][q8];
            const half8 af1 = *(const half8*)&xh[m16][32 + q8];
            #pragma unroll
            for (int n4 = 0; n4 < 4; ++n4) {
                acc[n4] = __builtin_amdgcn_mfma_f32_16x16x32_f16(af0, etf[n4][0], acc[n4], 0, 0, 0);
                acc[n4] = __builtin_amdgcn_mfma_f32_16x16x32_f16(af1, etf[n4][1], acc[n4], 0, 0, 0);
            }
        }

        // ---- acquire s(t-1): check speculative values, retry on stale tags ----
        if (t > 0) {
            const unsigned utag = (unsigned)t;
            for (;;) {
                if ((unsigned)(v0 >> 32) == utag && (unsigned)(v1 >> 32) == utag &&
                    (unsigned)(v2 >> 32) == utag && (unsigned)(v3 >> 32) == utag)
                    break;
                v0 = __hip_atomic_load(pb + 0 * (BT * DS), __ATOMIC_RELAXED, __HIP_MEMORY_SCOPE_AGENT);
                v1 = __hip_atomic_load(pb + 1 * (BT * DS), __ATOMIC_RELAXED, __HIP_MEMORY_SCOPE_AGENT);
                v2 = __hip_atomic_load(pb + 2 * (BT * DS), __ATOMIC_RELAXED, __HIP_MEMORY_SCOPE_AGENT);
                v3 = __hip_atomic_load(pb + 3 * (BT * DS), __ATOMIC_RELAXED, __HIP_MEMORY_SCOPE_AGENT);
            }
            const float ssum = __uint_as_float((unsigned)v0) + __uint_as_float((unsigned)v1)
                             + __uint_as_float((unsigned)v2) + __uint_as_float((unsigned)v3);
            xh[rs][DIN + cs] = (_Float16)ssum;
        } else {
            xh[rs][DIN + cs] = (_Float16)0.f;
        }
        __syncthreads();   // B1: state half ready

        // ---- encode phase B: k-tiles 2,3 ----
        {
            const half8 af2 = *(const half8*)&xh[m16][64 + q8];
            const half8 af3 = *(const half8*)&xh[m16][96 + q8];
            #pragma unroll
            for (int n4 = 0; n4 < 4; ++n4) {
                acc[n4] = __builtin_amdgcn_mfma_f32_16x16x32_f16(af2, etf[n4][2], acc[n4], 0, 0, 0);
                acc[n4] = __builtin_amdgcn_mfma_f32_16x16x32_f16(af3, etf[n4][3], acc[n4], 0, 0, 0);
            }
        }

        // ---- epilogue: rows 0..7 live in lanes 0..31 (row=(l>>4)*4+reg) ----
        if (l < 32) {
            const int rq = (l >> 4) << 2;
            #pragma unroll
            for (int n4 = 0; n4 < 4; ++n4) {
                const int n = w * 64 + n4 * 16 + m16;
                Ash[rq + 0][n] = (_Float16)fabsf(gv[n4] * acc[n4][0] + bv[n4]);
                Ash[rq + 1][n] = (_Float16)fabsf(gv[n4] * acc[n4][1] + bv[n4]);
                Ash[rq + 2][n] = (_Float16)fabsf(gv[n4] * acc[n4][2] + bv[n4]);
                Ash[rq + 3][n] = (_Float16)fabsf(gv[n4] * acc[n4][3] + bv[n4]);
            }
        }
        __syncthreads();   // B2: activations ready

        if (t == T_ - 1) {
            // ---- final projection: out += A_tile @ dec_tile ----
            for (int idx = tid; idx < BT * DOUT; idx += THREADS) {
                const int r = idx / DOUT;
                const int d = idx % DOUT;
                float o = 0.f;
                #pragma unroll 8
                for (int n = 0; n < NT; ++n)
                    o += (float)Ash[r][n] * dec[(size_t)(n0 + n) * DOUT + d];
                atomicAdd(&out[(size_t)(b0 + r) * DOUT + d], o);
            }
            return;
        }

        // ---- decode (waves 0-3, full K=512) + u_{t+1} staging (waves 4-7) ----
        if (w < 4) {
            f32x4 d0 = (f32x4){0.f, 0.f, 0.f, 0.f};
            f32x4 d1 = (f32x4){0.f, 0.f, 0.f, 0.f};
            #pragma unroll
            for (int kt = 0; kt < 16; kt += 2) {
                const half8 a0 = *(const half8*)&Ash[m16][kt * 32 + q8];
                d0 = __builtin_amdgcn_mfma_f32_16x16x32_f16(a0, sdf[kt], d0, 0, 0, 0);
                const half8 a1 = *(const half8*)&Ash[m16][(kt + 1) * 32 + q8];
                d1 = __builtin_amdgcn_mfma_f32_16x16x32_f16(a1, sdf[kt + 1], d1, 0, 0, 0);
            }
            d0[0] += d1[0]; d0[1] += d1[1]; d0[2] += d1[2]; d0[3] += d1[3];
            // C/D: col = lane&15 -> state col 16w+m16; rows 0..7 in lanes 0..31
            if (l < 32) {
                const int rq = (l >> 4) << 2;
                unsigned long long* pw = psq + (size_t)(t & 1) * PSQ_ELEMS
                    + (((size_t)bt * NTILES + nt) * BT) * DS + 16 * w + m16;
                const unsigned long long tg = (unsigned long long)(unsigned)(t + 1) << 32;
                #pragma unroll
                for (int r = 0; r < 4; ++r) {
                    __hip_atomic_store(pw + (size_t)(rq + r) * DS,
                                       tg | (unsigned long long)__float_as_uint(d0[r]),
                                       __ATOMIC_RELAXED, __HIP_MEMORY_SCOPE_AGENT);
                }
            }
        } else if (l < 32) {
            // stage u_{t+1}: 4 waves x 32 lanes = 128 float4 loads
            const int idx = ((w - 4) << 5) + l;     // 0..127
            const int r = idx >> 4, c = (idx & 15) << 2;
            const float4 uv =
                *(const float4*)&seq[((size_t)(b0 + r) * T_ + (t + 1)) * DIN + c];
            _Float16* p = &xh[r][c];
            p[0] = (_Float16)uv.x; p[1] = (_Float16)uv.y;
            p[2] = (_Float16)uv.z; p[3] = (_Float16)uv.w;
        }
        __syncthreads();   // B3: decode reads of Ash done + u_{t+1} staged
        // no drain, no counter — tag rides with the data
    }
}

extern "C" void kernel_launch(void* const* d_in, const int* in_sizes, int n_in,
                              void* d_out, int out_size, void* d_ws, size_t ws_size,
                              hipStream_t stream) {
    const float* seq  = (const float*)d_in[0];
    const float* enc  = (const float*)d_in[1];
    const float* bias = (const float*)d_in[2];
    const float* gain = (const float*)d_in[3];
    const float* sd   = (const float*)d_in[4];
    const float* dec  = (const float*)d_in[5];
    float* out = (float*)d_out;
    float* ws  = (float*)d_ws;   // psq[2] (2 MB) | EtSw | SdSw  (~2.8 MB)

    pre_kernel<<<dim3(1024), dim3(256), 0, stream>>>(enc, sd, ws, out);

    unsigned long long* psq = (unsigned long long*)ws;
    const _Float16* EtSw = (const _Float16*)(ws + ETSW_OFF);
    const _Float16* SdSw = (const _Float16*)(ws + SDSW_OFF);

    persist_kernel<<<dim3(NWG), dim3(THREADS), 0, stream>>>(
        seq, EtSw, SdSw, bias, gain, dec, psq, out);
}